// Round 1
// baseline (1130.010 us; speedup 1.0000x reference)
//
#include <hip/hip_runtime.h>
#include <math.h>

#define KNN 16
#define NPTS 8192
#define PTCH 256
#define NPATCH 32
#define NBATCH 4

__global__ void zero2_kernel(float* out) { out[0] = 0.0f; out[1] = 0.0f; }

// One Jacobi rotation on symmetric 3x3 (p,q), updating the third row/col (r)
// and the two affected eigenvector columns.
__device__ __forceinline__ void jrot(double& app, double& aqq, double& apq,
                                     double& arp, double& arq,
                                     double& vp0, double& vq0,
                                     double& vp1, double& vq1,
                                     double& vp2, double& vq2)
{
    double g = apq;
    if (g == 0.0) return;
    double theta = (aqq - app) / (2.0 * g);
    double at = fabs(theta);
    double t = (at > 1.0e154) ? (0.5 / theta)
                              : (copysign(1.0, theta) / (at + sqrt(theta * theta + 1.0)));
    double c = 1.0 / sqrt(t * t + 1.0);
    double s = t * c;
    double tau = s / (1.0 + c);
    app -= t * g;
    aqq += t * g;
    apq = 0.0;
    double rp = arp, rq = arq;
    arp = rp - s * (rq + tau * rp);
    arq = rq + s * (rp - tau * rq);
    double p0 = vp0, q0 = vq0;
    vp0 = p0 - s * (q0 + tau * p0); vq0 = q0 + s * (p0 - tau * q0);
    double p1 = vp1, q1 = vq1;
    vp1 = p1 - s * (q1 + tau * p1); vq1 = q1 + s * (p1 - tau * q1);
    double p2 = vp2, q2 = vq2;
    vp2 = p2 - s * (q2 + tau * p2); vq2 = q2 + s * (p2 - tau * q2);
}

// fp64 cyclic Jacobi for symmetric 3x3. Returns eigvec of smallest eigval,
// the smallest eigval and the trace-sum of eigvals.
__device__ __forceinline__ void eig3(double a00, double a11, double a22,
                                     double a01, double a02, double a12,
                                     double& nx, double& ny, double& nz,
                                     double& lmin, double& lsum)
{
    double v00 = 1, v01 = 0, v02 = 0;
    double v10 = 0, v11 = 1, v12 = 0;
    double v20 = 0, v21 = 0, v22 = 1;
    double scale = fabs(a00) + fabs(a11) + fabs(a22) + fabs(a01) + fabs(a02) + fabs(a12);
    if (scale > 0.0) {
        for (int sweep = 0; sweep < 8; ++sweep) {
            double off = fabs(a01) + fabs(a02) + fabs(a12);
            if (off <= scale * 1e-28) break;
            jrot(a00, a11, a01, a02, a12, v00, v01, v10, v11, v20, v21);  // (0,1)
            jrot(a00, a22, a02, a01, a12, v00, v02, v10, v12, v20, v22);  // (0,2)
            jrot(a11, a22, a12, a01, a02, v01, v02, v11, v12, v21, v22);  // (1,2)
        }
    }
    lsum = a00 + a11 + a22;
    lmin = a00; nx = v00; ny = v10; nz = v20;
    if (a11 < lmin) { lmin = a11; nx = v01; ny = v11; nz = v21; }
    if (a22 < lmin) { lmin = a22; nx = v02; ny = v12; nz = v22; }
}

// Sorted-ascending top-16 of u64 keys (d2_bits<<32 | idx): single gate compare,
// branchless bubble pass. Key uniqueness gives exact top_k tie semantics.
__device__ __forceinline__ void insert16(unsigned long long key, unsigned long long* L)
{
    if (key < L[KNN - 1]) {
        L[KNN - 1] = key;
        #pragma unroll
        for (int m = KNN - 1; m >= 1; --m) {
            unsigned long long a = L[m - 1], b = L[m];
            unsigned long long lo = (b < a) ? b : a;
            unsigned long long hi = (b < a) ? a : b;
            L[m - 1] = lo;
            L[m] = hi;
        }
    }
}

// Block = 256 threads handling 128 queries of one patch-half. Thread t and
// t+128 are partners on query (t&127): each scans half of every tile's
// candidates (j<128 vs j>=128), lists merged afterwards. Low half then does
// the global eigensolve while high half does the patch kNN + eigensolve.
__global__ void __launch_bounds__(256)
spl_main(const float* __restrict__ pts, float* __restrict__ out)
{
    __shared__ float4 tile4[PTCH];                    // 4 KB candidate tile (padded)
    __shared__ float4 pbuf4[PTCH];                    // 4 KB own patch (persistent)
    __shared__ unsigned long long mergeBuf[128 * KNN];// 16 KB partner lists
    __shared__ double xbuf[128 * 4];                  // 4 KB patch normal+sv
    __shared__ double rb[8];

    const int t = threadIdx.x;
    const int p = blockIdx.x;      // patch
    const int half = blockIdx.y;   // query half of the patch
    const int b = blockIdx.z;      // batch

    const float* base = pts + (size_t)b * (NPTS * 3);
    const int q = t & 127;
    const int qi = p * PTCH + half * 128 + q;

    const float qx = base[qi * 3 + 0];
    const float qy = base[qi * 3 + 1];
    const float qz = base[qi * 3 + 2];

    // Stage own patch into padded LDS (read later for patch kNN + cov gather).
    {
        const float* src = base + p * (PTCH * 3);
        float* dst = (float*)pbuf4;
        #pragma unroll
        for (int s = 0; s < 3; ++s) {
            int f = t + s * 256;
            int j = f / 3;
            int c = f - 3 * j;
            dst[j * 4 + c] = src[f];
        }
    }

    unsigned long long gl[KNN];
    #pragma unroll
    for (int m = 0; m < KNN; ++m) gl[m] = 0xFFFFFFFFFFFFFFFFull;

    const int j0 = (t < 128) ? 0 : 128;   // wave-uniform candidate split

    for (int tl = 0; tl < NPATCH; ++tl) {
        __syncthreads();
        const float* src = base + tl * (PTCH * 3);
        float* dst = (float*)tile4;
        #pragma unroll
        for (int s = 0; s < 3; ++s) {
            int f = t + s * 256;
            int j = f / 3;
            int c = f - 3 * j;
            dst[j * 4 + c] = src[f];
        }
        __syncthreads();
        const int gbase = tl * PTCH;
        for (int j = j0; j < j0 + 128; ++j) {
            float4 cpt = tile4[j];                    // ds_read_b128 broadcast
            float dx = qx - cpt.x;
            float dy = qy - cpt.y;
            float dz = qz - cpt.z;
            float d2 = dx * dx + dy * dy + dz * dz;
            unsigned long long key =
                (((unsigned long long)__float_as_uint(d2)) << 32) |
                (unsigned int)(gbase + j);
            insert16(key, gl);
        }
    }

    __syncthreads();
    if (t >= 128) {
        #pragma unroll
        for (int m = 0; m < KNN; ++m) mergeBuf[q * KNN + m] = gl[m];
    }
    __syncthreads();

    double ngx = 0, ngy = 0, ngz = 0, svg = 0;

    if (t < 128) {
        // Merge partner's sorted list (early break: lists ascending, gate only shrinks).
        for (int m = 0; m < KNN; ++m) {
            unsigned long long key = mergeBuf[q * KNN + m];
            if (key >= gl[KNN - 1]) break;
            insert16(key, gl);
        }
        // Global covariance in fp64 (centered diffs are exact in fp64).
        double c00 = 0, c11 = 0, c22 = 0, c01 = 0, c02 = 0, c12 = 0;
        const double qxd = qx, qyd = qy, qzd = qz;
        #pragma unroll
        for (int m = 0; m < KNN; ++m) {
            int idx = (int)(unsigned int)(gl[m] & 0xFFFFFFFFull);
            double dx = (double)base[idx * 3 + 0] - qxd;
            double dy = (double)base[idx * 3 + 1] - qyd;
            double dz = (double)base[idx * 3 + 2] - qzd;
            c00 += dx * dx; c11 += dy * dy; c22 += dz * dz;
            c01 += dx * dy; c02 += dx * dz; c12 += dy * dz;
        }
        double lmin, lsum;
        eig3(c00, c11, c22, c01, c02, c12, ngx, ngy, ngz, lmin, lsum);
        svg = lmin / lsum;
    } else {
        // Patch kNN over the 256 patch points (local indices).
        unsigned long long pl[KNN];
        #pragma unroll
        for (int m = 0; m < KNN; ++m) pl[m] = 0xFFFFFFFFFFFFFFFFull;
        for (int j = 0; j < PTCH; ++j) {
            float4 cpt = pbuf4[j];
            float dx = qx - cpt.x;
            float dy = qy - cpt.y;
            float dz = qz - cpt.z;
            float d2 = dx * dx + dy * dy + dz * dz;
            unsigned long long key =
                (((unsigned long long)__float_as_uint(d2)) << 32) | (unsigned int)j;
            insert16(key, pl);
        }
        double c00 = 0, c11 = 0, c22 = 0, c01 = 0, c02 = 0, c12 = 0;
        const double qxd = qx, qyd = qy, qzd = qz;
        #pragma unroll
        for (int m = 0; m < KNN; ++m) {
            int idx = (int)(unsigned int)(pl[m] & 0xFFFFFFFFull);
            float4 cpt = pbuf4[idx];
            double dx = (double)cpt.x - qxd;
            double dy = (double)cpt.y - qyd;
            double dz = (double)cpt.z - qzd;
            c00 += dx * dx; c11 += dy * dy; c22 += dz * dz;
            c01 += dx * dy; c02 += dx * dz; c12 += dy * dz;
        }
        double nx, ny, nz, lmin, lsum;
        eig3(c00, c11, c22, c01, c02, c12, nx, ny, nz, lmin, lsum);
        xbuf[q * 4 + 0] = nx;
        xbuf[q * 4 + 1] = ny;
        xbuf[q * 4 + 2] = nz;
        xbuf[q * 4 + 3] = lmin / lsum;
    }

    __syncthreads();

    double ln = 0.0, lsv = 0.0;
    if (t < 128) {
        double npx = xbuf[q * 4 + 0];
        double npy = xbuf[q * 4 + 1];
        double npz = xbuf[q * 4 + 2];
        double svp = xbuf[q * 4 + 3];
        double dx = fabs(npx) - fabs(ngx);
        double dy = fabs(npy) - fabs(ngy);
        double dz = fabs(npz) - fabs(ngz);
        ln = sqrt(dx * dx + dy * dy + dz * dz);
        double ds = svp - svg;
        lsv = ds * ds;
    }

    // Block reduction (high half contributes zeros).
    #pragma unroll
    for (int o = 32; o > 0; o >>= 1) {
        ln  += __shfl_down(ln, o);
        lsv += __shfl_down(lsv, o);
    }
    const int wid = t >> 6;
    if ((t & 63) == 0) { rb[wid * 2 + 0] = ln; rb[wid * 2 + 1] = lsv; }
    __syncthreads();
    if (t == 0) {
        double sln = rb[0] + rb[2] + rb[4] + rb[6];
        double ssv = rb[1] + rb[3] + rb[5] + rb[7];
        const double inv = 1.0 / (double)(NBATCH * NPTS);
        atomicAdd(&out[0], (float)(sln * inv));
        atomicAdd(&out[1], (float)(ssv * inv));
    }
}

extern "C" void kernel_launch(void* const* d_in, const int* in_sizes, int n_in,
                              void* d_out, int out_size, void* d_ws, size_t ws_size,
                              hipStream_t stream)
{
    const float* pts = (const float*)d_in[0];
    float* out = (float*)d_out;
    // d_out is poisoned 0xAA before every call — zero it on-stream first.
    hipLaunchKernelGGL(zero2_kernel, dim3(1), dim3(1), 0, stream, out);
    dim3 grid(NPATCH, 2, NBATCH);
    hipLaunchKernelGGL(spl_main, grid, dim3(256), 0, stream, pts, out);
}

// Round 2
// 440.002 us; speedup vs baseline: 2.5682x; 2.5682x over previous
//
#include <hip/hip_runtime.h>
#include <math.h>

#define KNN 16
#define NPTS 8192
#define PTCH 256
#define NPATCH 32
#define NBATCH 4

__global__ void zero2_kernel(float* out) { out[0] = 0.0f; out[1] = 0.0f; }

// One Jacobi rotation on symmetric 3x3 (p,q), updating the third row/col (r)
// and the two affected eigenvector columns.
__device__ __forceinline__ void jrot(double& app, double& aqq, double& apq,
                                     double& arp, double& arq,
                                     double& vp0, double& vq0,
                                     double& vp1, double& vq1,
                                     double& vp2, double& vq2)
{
    double g = apq;
    if (g == 0.0) return;
    double theta = (aqq - app) / (2.0 * g);
    double at = fabs(theta);
    double t = (at > 1.0e154) ? (0.5 / theta)
                              : (copysign(1.0, theta) / (at + sqrt(theta * theta + 1.0)));
    double c = 1.0 / sqrt(t * t + 1.0);
    double s = t * c;
    double tau = s / (1.0 + c);
    app -= t * g;
    aqq += t * g;
    apq = 0.0;
    double rp = arp, rq = arq;
    arp = rp - s * (rq + tau * rp);
    arq = rq + s * (rp - tau * rq);
    double p0 = vp0, q0 = vq0;
    vp0 = p0 - s * (q0 + tau * p0); vq0 = q0 + s * (p0 - tau * q0);
    double p1 = vp1, q1 = vq1;
    vp1 = p1 - s * (q1 + tau * p1); vq1 = q1 + s * (p1 - tau * q1);
    double p2 = vp2, q2 = vq2;
    vp2 = p2 - s * (q2 + tau * p2); vq2 = q2 + s * (p2 - tau * q2);
}

// fp64 cyclic Jacobi for symmetric 3x3 -> eigvec of smallest eigval, lmin, trace-sum.
__device__ __forceinline__ void eig3(double a00, double a11, double a22,
                                     double a01, double a02, double a12,
                                     double& nx, double& ny, double& nz,
                                     double& lmin, double& lsum)
{
    double v00 = 1, v01 = 0, v02 = 0;
    double v10 = 0, v11 = 1, v12 = 0;
    double v20 = 0, v21 = 0, v22 = 1;
    double scale = fabs(a00) + fabs(a11) + fabs(a22) + fabs(a01) + fabs(a02) + fabs(a12);
    if (scale > 0.0) {
        for (int sweep = 0; sweep < 6; ++sweep) {
            double off = fabs(a01) + fabs(a02) + fabs(a12);
            if (off <= scale * 1e-15) break;
            jrot(a00, a11, a01, a02, a12, v00, v01, v10, v11, v20, v21);  // (0,1)
            jrot(a00, a22, a02, a01, a12, v00, v02, v10, v12, v20, v22);  // (0,2)
            jrot(a11, a22, a12, a01, a02, v01, v02, v11, v12, v21, v22);  // (1,2)
        }
    }
    lsum = a00 + a11 + a22;
    lmin = a00; nx = v00; ny = v10; nz = v20;
    if (a11 < lmin) { lmin = a11; nx = v01; ny = v11; nz = v21; }
    if (a22 < lmin) { lmin = a22; nx = v02; ny = v12; nz = v22; }
}

// u32 key: (d2 float bits, low 13 mantissa bits cleared) | idx(13b).
// d2 >= 0 -> float bits monotone; equal quantized d2 -> lower idx wins (top_k tie rule).
__device__ __forceinline__ unsigned mkkey(float d2, unsigned idx) {
    return (__float_as_uint(d2) & 0xFFFFE000u) | idx;
}

// Caller guarantees key < L[15]. Sorted-ascending bubble: 2 ops/CE (v_min/v_max_u32).
__device__ __forceinline__ void insert16(unsigned key, unsigned* L)
{
    L[KNN - 1] = key;
    #pragma unroll
    for (int m = KNN - 1; m >= 1; --m) {
        unsigned a = L[m - 1], b = L[m];
        L[m - 1] = min(a, b);
        L[m]     = max(a, b);
    }
}

__device__ __forceinline__ float dist2(float qx, float qy, float qz, float4 c) {
    float dx = qx - c.x, dy = qy - c.y, dz = qz - c.z;
    return dx * dx + dy * dy + dz * dz;
}

// Block = 256 threads, 128 queries (one patch-half). Threads t and t+128 are
// partners on query q=t&127, each scanning half of every tile's candidates.
// After merge: low waves do global eigensolve, high waves do patch kNN + eigensolve.
__global__ void __launch_bounds__(256)
spl_main(const float* __restrict__ pts, float* __restrict__ out)
{
    __shared__ float4 tile4[PTCH];               // 4 KB candidate tile (padded)
    __shared__ float4 pbuf4[PTCH];               // 4 KB own patch (persistent)
    __shared__ unsigned mergeBuf[128 * KNN];     // 8 KB partner lists (u32 keys)
    __shared__ double xbuf[128 * 4];             // 4 KB patch normal+sv
    __shared__ double rb[8];

    const int t = threadIdx.x;
    const int p = blockIdx.x;      // patch
    const int half = blockIdx.y;   // query half of the patch
    const int b = blockIdx.z;      // batch

    const float* base = pts + (size_t)b * (NPTS * 3);
    const int q = t & 127;
    const int qi = p * PTCH + half * 128 + q;

    const float qx = base[qi * 3 + 0];
    const float qy = base[qi * 3 + 1];
    const float qz = base[qi * 3 + 2];

    // Stage own patch into padded LDS.
    {
        const float* src = base + p * (PTCH * 3);
        float* dst = (float*)pbuf4;
        #pragma unroll
        for (int s = 0; s < 3; ++s) {
            int f = t + s * 256;
            int j = f / 3;
            int c = f - 3 * j;
            dst[j * 4 + c] = src[f];
        }
    }

    unsigned gl[KNN];
    #pragma unroll
    for (int m = 0; m < KNN; ++m) gl[m] = 0xFFFFFFFFu;

    const int j0 = (t < 128) ? 0 : 128;   // wave-uniform candidate split

    for (int tl = 0; tl < NPATCH; ++tl) {
        __syncthreads();
        const float* src = base + tl * (PTCH * 3);
        float* dst = (float*)tile4;
        #pragma unroll
        for (int s = 0; s < 3; ++s) {
            int f = t + s * 256;
            int j = f / 3;
            int c = f - 3 * j;
            dst[j * 4 + c] = src[f];
        }
        __syncthreads();
        const unsigned gb = (unsigned)(tl * PTCH);
        #pragma unroll 1
        for (int j = j0; j < j0 + 128; j += 8) {
            // 8 independent d2 chains (broadcast ds_read_b128, same addr all lanes)
            float4 c0 = tile4[j + 0];
            float4 c1 = tile4[j + 1];
            float4 c2 = tile4[j + 2];
            float4 c3 = tile4[j + 3];
            float4 c4 = tile4[j + 4];
            float4 c5 = tile4[j + 5];
            float4 c6 = tile4[j + 6];
            float4 c7 = tile4[j + 7];
            unsigned k0 = mkkey(dist2(qx, qy, qz, c0), gb + j + 0);
            unsigned k1 = mkkey(dist2(qx, qy, qz, c1), gb + j + 1);
            unsigned k2 = mkkey(dist2(qx, qy, qz, c2), gb + j + 2);
            unsigned k3 = mkkey(dist2(qx, qy, qz, c3), gb + j + 3);
            unsigned k4 = mkkey(dist2(qx, qy, qz, c4), gb + j + 4);
            unsigned k5 = mkkey(dist2(qx, qy, qz, c5), gb + j + 5);
            unsigned k6 = mkkey(dist2(qx, qy, qz, c6), gb + j + 6);
            unsigned k7 = mkkey(dist2(qx, qy, qz, c7), gb + j + 7);
            unsigned m03 = min(min(k0, k1), min(k2, k3));
            if (m03 < gl[KNN - 1]) {
                if (k0 < gl[KNN - 1]) insert16(k0, gl);
                if (k1 < gl[KNN - 1]) insert16(k1, gl);
                if (k2 < gl[KNN - 1]) insert16(k2, gl);
                if (k3 < gl[KNN - 1]) insert16(k3, gl);
            }
            unsigned m47 = min(min(k4, k5), min(k6, k7));
            if (m47 < gl[KNN - 1]) {
                if (k4 < gl[KNN - 1]) insert16(k4, gl);
                if (k5 < gl[KNN - 1]) insert16(k5, gl);
                if (k6 < gl[KNN - 1]) insert16(k6, gl);
                if (k7 < gl[KNN - 1]) insert16(k7, gl);
            }
        }
    }

    __syncthreads();
    if (t >= 128) {
        #pragma unroll
        for (int m = 0; m < KNN; ++m) mergeBuf[q * KNN + m] = gl[m];
    }
    __syncthreads();

    double ngx = 0, ngy = 0, ngz = 0, svg = 0;

    if (t < 128) {
        // Merge partner's sorted list (ascending; gate only shrinks -> early break).
        for (int m = 0; m < KNN; ++m) {
            unsigned key = mergeBuf[q * KNN + m];
            if (key >= gl[KNN - 1]) break;
            insert16(key, gl);
        }
        // Global covariance in fp64.
        double c00 = 0, c11 = 0, c22 = 0, c01 = 0, c02 = 0, c12 = 0;
        const double qxd = qx, qyd = qy, qzd = qz;
        #pragma unroll
        for (int m = 0; m < KNN; ++m) {
            int idx = (int)(gl[m] & 0x1FFFu);
            double dx = (double)base[idx * 3 + 0] - qxd;
            double dy = (double)base[idx * 3 + 1] - qyd;
            double dz = (double)base[idx * 3 + 2] - qzd;
            c00 += dx * dx; c11 += dy * dy; c22 += dz * dz;
            c01 += dx * dy; c02 += dx * dz; c12 += dy * dz;
        }
        double lmin, lsum;
        eig3(c00, c11, c22, c01, c02, c12, ngx, ngy, ngz, lmin, lsum);
        svg = lmin / lsum;
    } else {
        // Patch kNN over the 256 patch points (local indices in key low bits).
        unsigned pl[KNN];
        #pragma unroll
        for (int m = 0; m < KNN; ++m) pl[m] = 0xFFFFFFFFu;
        #pragma unroll 1
        for (int j = 0; j < PTCH; j += 8) {
            float4 c0 = pbuf4[j + 0];
            float4 c1 = pbuf4[j + 1];
            float4 c2 = pbuf4[j + 2];
            float4 c3 = pbuf4[j + 3];
            float4 c4 = pbuf4[j + 4];
            float4 c5 = pbuf4[j + 5];
            float4 c6 = pbuf4[j + 6];
            float4 c7 = pbuf4[j + 7];
            unsigned k0 = mkkey(dist2(qx, qy, qz, c0), j + 0);
            unsigned k1 = mkkey(dist2(qx, qy, qz, c1), j + 1);
            unsigned k2 = mkkey(dist2(qx, qy, qz, c2), j + 2);
            unsigned k3 = mkkey(dist2(qx, qy, qz, c3), j + 3);
            unsigned k4 = mkkey(dist2(qx, qy, qz, c4), j + 4);
            unsigned k5 = mkkey(dist2(qx, qy, qz, c5), j + 5);
            unsigned k6 = mkkey(dist2(qx, qy, qz, c6), j + 6);
            unsigned k7 = mkkey(dist2(qx, qy, qz, c7), j + 7);
            unsigned m03 = min(min(k0, k1), min(k2, k3));
            if (m03 < pl[KNN - 1]) {
                if (k0 < pl[KNN - 1]) insert16(k0, pl);
                if (k1 < pl[KNN - 1]) insert16(k1, pl);
                if (k2 < pl[KNN - 1]) insert16(k2, pl);
                if (k3 < pl[KNN - 1]) insert16(k3, pl);
            }
            unsigned m47 = min(min(k4, k5), min(k6, k7));
            if (m47 < pl[KNN - 1]) {
                if (k4 < pl[KNN - 1]) insert16(k4, pl);
                if (k5 < pl[KNN - 1]) insert16(k5, pl);
                if (k6 < pl[KNN - 1]) insert16(k6, pl);
                if (k7 < pl[KNN - 1]) insert16(k7, pl);
            }
        }
        double c00 = 0, c11 = 0, c22 = 0, c01 = 0, c02 = 0, c12 = 0;
        const double qxd = qx, qyd = qy, qzd = qz;
        #pragma unroll
        for (int m = 0; m < KNN; ++m) {
            int idx = (int)(pl[m] & 0x1FFFu);
            float4 cpt = pbuf4[idx];
            double dx = (double)cpt.x - qxd;
            double dy = (double)cpt.y - qyd;
            double dz = (double)cpt.z - qzd;
            c00 += dx * dx; c11 += dy * dy; c22 += dz * dz;
            c01 += dx * dy; c02 += dx * dz; c12 += dy * dz;
        }
        double nx, ny, nz, lmin, lsum;
        eig3(c00, c11, c22, c01, c02, c12, nx, ny, nz, lmin, lsum);
        xbuf[q * 4 + 0] = nx;
        xbuf[q * 4 + 1] = ny;
        xbuf[q * 4 + 2] = nz;
        xbuf[q * 4 + 3] = lmin / lsum;
    }

    __syncthreads();

    double ln = 0.0, lsv = 0.0;
    if (t < 128) {
        double npx = xbuf[q * 4 + 0];
        double npy = xbuf[q * 4 + 1];
        double npz = xbuf[q * 4 + 2];
        double svp = xbuf[q * 4 + 3];
        double dx = fabs(npx) - fabs(ngx);
        double dy = fabs(npy) - fabs(ngy);
        double dz = fabs(npz) - fabs(ngz);
        ln = sqrt(dx * dx + dy * dy + dz * dz);
        double ds = svp - svg;
        lsv = ds * ds;
    }

    // Block reduction (high half contributes zeros).
    #pragma unroll
    for (int o = 32; o > 0; o >>= 1) {
        ln  += __shfl_down(ln, o);
        lsv += __shfl_down(lsv, o);
    }
    const int wid = t >> 6;
    if ((t & 63) == 0) { rb[wid * 2 + 0] = ln; rb[wid * 2 + 1] = lsv; }
    __syncthreads();
    if (t == 0) {
        double sln = rb[0] + rb[2] + rb[4] + rb[6];
        double ssv = rb[1] + rb[3] + rb[5] + rb[7];
        const double inv = 1.0 / (double)(NBATCH * NPTS);
        atomicAdd(&out[0], (float)(sln * inv));
        atomicAdd(&out[1], (float)(ssv * inv));
    }
}

extern "C" void kernel_launch(void* const* d_in, const int* in_sizes, int n_in,
                              void* d_out, int out_size, void* d_ws, size_t ws_size,
                              hipStream_t stream)
{
    const float* pts = (const float*)d_in[0];
    float* out = (float*)d_out;
    hipLaunchKernelGGL(zero2_kernel, dim3(1), dim3(1), 0, stream, out);
    dim3 grid(NPATCH, 2, NBATCH);
    hipLaunchKernelGGL(spl_main, grid, dim3(256), 0, stream, pts, out);
}

// Round 3
// 280.714 us; speedup vs baseline: 4.0255x; 1.5674x over previous
//
#include <hip/hip_runtime.h>
#include <math.h>

#define KNN 16
#define NPTS 8192
#define PTCH 256
#define NPATCH 32
#define NBATCH 4
#define NQ 64   // queries per block

__global__ void zero2_kernel(float* out) { out[0] = 0.0f; out[1] = 0.0f; }

// One Jacobi rotation on symmetric 3x3 (p,q), updating third row/col + eigvec cols.
__device__ __forceinline__ void jrot(double& app, double& aqq, double& apq,
                                     double& arp, double& arq,
                                     double& vp0, double& vq0,
                                     double& vp1, double& vq1,
                                     double& vp2, double& vq2)
{
    double g = apq;
    if (g == 0.0) return;
    double theta = (aqq - app) / (2.0 * g);
    double at = fabs(theta);
    double t = (at > 1.0e154) ? (0.5 / theta)
                              : (copysign(1.0, theta) / (at + sqrt(theta * theta + 1.0)));
    double c = 1.0 / sqrt(t * t + 1.0);
    double s = t * c;
    double tau = s / (1.0 + c);
    app -= t * g;
    aqq += t * g;
    apq = 0.0;
    double rp = arp, rq = arq;
    arp = rp - s * (rq + tau * rp);
    arq = rq + s * (rp - tau * rq);
    double p0 = vp0, q0 = vq0;
    vp0 = p0 - s * (q0 + tau * p0); vq0 = q0 + s * (p0 - tau * q0);
    double p1 = vp1, q1 = vq1;
    vp1 = p1 - s * (q1 + tau * p1); vq1 = q1 + s * (p1 - tau * q1);
    double p2 = vp2, q2 = vq2;
    vp2 = p2 - s * (q2 + tau * p2); vq2 = q2 + s * (p2 - tau * q2);
}

// fp64 cyclic Jacobi for symmetric 3x3 -> eigvec of smallest eigval, lmin, trace-sum.
__device__ __forceinline__ void eig3(double a00, double a11, double a22,
                                     double a01, double a02, double a12,
                                     double& nx, double& ny, double& nz,
                                     double& lmin, double& lsum)
{
    double v00 = 1, v01 = 0, v02 = 0;
    double v10 = 0, v11 = 1, v12 = 0;
    double v20 = 0, v21 = 0, v22 = 1;
    double scale = fabs(a00) + fabs(a11) + fabs(a22) + fabs(a01) + fabs(a02) + fabs(a12);
    if (scale > 0.0) {
        for (int sweep = 0; sweep < 6; ++sweep) {
            double off = fabs(a01) + fabs(a02) + fabs(a12);
            if (off <= scale * 1e-15) break;
            jrot(a00, a11, a01, a02, a12, v00, v01, v10, v11, v20, v21);
            jrot(a00, a22, a02, a01, a12, v00, v02, v10, v12, v20, v22);
            jrot(a11, a22, a12, a01, a02, v01, v02, v11, v12, v21, v22);
        }
    }
    lsum = a00 + a11 + a22;
    lmin = a00; nx = v00; ny = v10; nz = v20;
    if (a11 < lmin) { lmin = a11; nx = v01; ny = v11; nz = v21; }
    if (a22 < lmin) { lmin = a22; nx = v02; ny = v12; nz = v22; }
}

// u32 key: (d2 float bits, low 13 mantissa bits cleared) | idx(13b).
__device__ __forceinline__ unsigned mkkey(float d2, unsigned idx) {
    return (__float_as_uint(d2) & 0xFFFFE000u) | idx;
}

// Caller guarantees key < L[15]. Sorted-ascending bubble (v_min/v_max pairs).
__device__ __forceinline__ void insert16(unsigned key, unsigned* L)
{
    L[KNN - 1] = key;
    #pragma unroll
    for (int m = KNN - 1; m >= 1; --m) {
        unsigned a = L[m - 1], b = L[m];
        L[m - 1] = min(a, b);
        L[m]     = max(a, b);
    }
}

__device__ __forceinline__ float dist2(float qx, float qy, float qz, float4 c) {
    float dx = qx - c.x, dy = qy - c.y, dz = qz - c.z;
    return dx * dx + dy * dy + dz * dz;
}

// Branchless push into 4-deep register shift-buffer gated by current L[15].
#define PUSH(K) { bool pass_ = (K) < gl[KNN - 1];            \
    b3 = pass_ ? b2 : b3; b2 = pass_ ? b1 : b2;              \
    b1 = pass_ ? b0 : b1; b0 = pass_ ? (K) : b0;             \
    cnt += pass_ ? 1 : 0; }

#define FLUSHBODY() {                                         \
    if (cnt > 0 && b0 < gl[KNN - 1]) insert16(b0, gl);        \
    if (cnt > 1 && b1 < gl[KNN - 1]) insert16(b1, gl);        \
    if (cnt > 2 && b2 < gl[KNN - 1]) insert16(b2, gl);        \
    if (cnt > 3 && b3 < gl[KNN - 1]) insert16(b3, gl);        \
    cnt = 0; }

#define CHECKMERGE() { if (__any(cnt >= 3)) { FLUSHBODY(); } }

// Block = 256 threads, 64 queries (quarter patch). 4 threads/query: wave w
// scans tiles [w*8, w*8+8) (2048 candidates) into a per-wave private LDS tile.
// Phase 2: wave0 merges 4 global lists + eig; waves1/2 do patch-kNN halves.
__global__ void __launch_bounds__(256)
spl_main(const float* __restrict__ pts, float* __restrict__ out)
{
    __shared__ float4 tileW[4][PTCH];          // 16 KB per-wave candidate tiles
    __shared__ float4 pbuf4[PTCH];             // 4 KB own patch
    __shared__ unsigned gLists[3][NQ * KNN];   // 12 KB waves1-3 global lists
    __shared__ unsigned pListBuf[NQ * KNN];    // 4 KB wave2 patch half-list
    __shared__ double xbuf[NQ * 4];            // 2 KB patch normal+sv

    const int t = threadIdx.x;
    const int w = t >> 6;          // wave id 0..3 (candidate substream)
    const int q = t & 63;          // query id within block
    const int p = blockIdx.x;      // patch
    const int quarter = blockIdx.y;
    const int b = blockIdx.z;

    const float* base = pts + (size_t)b * (NPTS * 3);
    const int qi = p * PTCH + quarter * NQ + q;

    const float qx = base[qi * 3 + 0];
    const float qy = base[qi * 3 + 1];
    const float qz = base[qi * 3 + 2];

    // Stage own patch into padded LDS (read in phase 2, after B1).
    {
        const float* src = base + p * (PTCH * 3);
        float* dst = (float*)pbuf4;
        #pragma unroll
        for (int s = 0; s < 3; ++s) {
            int f = t + s * 256;
            int j = f / 3;
            int c = f - 3 * j;
            dst[j * 4 + c] = src[f];
        }
    }

    unsigned gl[KNN];
    #pragma unroll
    for (int m = 0; m < KNN; ++m) gl[m] = 0xFFFFFFFFu;
    unsigned b0 = 0, b1 = 0, b2 = 0, b3 = 0;
    int cnt = 0;

    float4* myTile = tileW[w];

    // Prefetch first tile of this wave's substream (3 coalesced float4/lane).
    const float4* src4 = (const float4*)(base + (w * 8) * (PTCH * 3));
    float4 n0 = src4[q * 3 + 0];
    float4 n1 = src4[q * 3 + 1];
    float4 n2 = src4[q * 3 + 2];

    #pragma unroll 1
    for (int tl = 0; tl < 8; ++tl) {
        // Write prefetched tile into this wave's private LDS region.
        float4 c0 = n0, c1 = n1, c2 = n2;
        __asm__ __volatile__("" ::: "memory");
        myTile[q * 4 + 0] = make_float4(c0.x, c0.y, c0.z, 0.f);
        myTile[q * 4 + 1] = make_float4(c0.w, c1.x, c1.y, 0.f);
        myTile[q * 4 + 2] = make_float4(c1.z, c1.w, c2.x, 0.f);
        myTile[q * 4 + 3] = make_float4(c2.y, c2.z, c2.w, 0.f);
        __asm__ __volatile__("" ::: "memory");
        if (tl < 7) {
            const float4* nsrc = (const float4*)(base + (w * 8 + tl + 1) * (PTCH * 3));
            n0 = nsrc[q * 3 + 0];
            n1 = nsrc[q * 3 + 1];
            n2 = nsrc[q * 3 + 2];
        }
        const unsigned gb = (unsigned)((w * 8 + tl) * PTCH);
        int j0 = 0;
        if (tl == 0) {
            // Warmup: direct inserts to build a real gate before buffering.
            #pragma unroll 1
            for (int j = 0; j < 64; ++j) {
                unsigned k = mkkey(dist2(qx, qy, qz, myTile[j]), gb + j);
                if (k < gl[KNN - 1]) insert16(k, gl);
            }
            j0 = 64;
        }
        #pragma unroll 1
        for (int j = j0; j < PTCH; j += 8) {
            float4 d0 = myTile[j + 0];
            float4 d1 = myTile[j + 1];
            float4 d2v = myTile[j + 2];
            float4 d3 = myTile[j + 3];
            float4 d4 = myTile[j + 4];
            float4 d5 = myTile[j + 5];
            float4 d6 = myTile[j + 6];
            float4 d7 = myTile[j + 7];
            unsigned k0 = mkkey(dist2(qx, qy, qz, d0), gb + j + 0);
            unsigned k1 = mkkey(dist2(qx, qy, qz, d1), gb + j + 1);
            unsigned k2 = mkkey(dist2(qx, qy, qz, d2v), gb + j + 2);
            unsigned k3 = mkkey(dist2(qx, qy, qz, d3), gb + j + 3);
            unsigned k4 = mkkey(dist2(qx, qy, qz, d4), gb + j + 4);
            unsigned k5 = mkkey(dist2(qx, qy, qz, d5), gb + j + 5);
            unsigned k6 = mkkey(dist2(qx, qy, qz, d6), gb + j + 6);
            unsigned k7 = mkkey(dist2(qx, qy, qz, d7), gb + j + 7);
            PUSH(k0); PUSH(k1); CHECKMERGE();
            PUSH(k2); PUSH(k3); CHECKMERGE();
            PUSH(k4); PUSH(k5); CHECKMERGE();
            PUSH(k6); PUSH(k7); CHECKMERGE();
        }
    }
    FLUSHBODY();   // final flush

    if (w >= 1) {
        #pragma unroll
        for (int m = 0; m < KNN; ++m) gLists[w - 1][q * KNN + m] = gl[m];
    }
    __syncthreads();   // B1: lists + pbuf ready

    double ngx = 0, ngy = 0, ngz = 0, svg = 0;
    unsigned pl[KNN];

    if (w == 0) {
        // Merge the other 3 sorted partial lists (early break: ascending).
        for (int wl = 0; wl < 3; ++wl) {
            for (int m = 0; m < KNN; ++m) {
                unsigned key = gLists[wl][q * KNN + m];
                if (key >= gl[KNN - 1]) break;
                insert16(key, gl);
            }
        }
        // Global covariance in fp64.
        double c00 = 0, c11 = 0, c22 = 0, c01 = 0, c02 = 0, c12 = 0;
        const double qxd = qx, qyd = qy, qzd = qz;
        #pragma unroll
        for (int m = 0; m < KNN; ++m) {
            int idx = (int)(gl[m] & 0x1FFFu);
            double dx = (double)base[idx * 3 + 0] - qxd;
            double dy = (double)base[idx * 3 + 1] - qyd;
            double dz = (double)base[idx * 3 + 2] - qzd;
            c00 += dx * dx; c11 += dy * dy; c22 += dz * dz;
            c01 += dx * dy; c02 += dx * dz; c12 += dy * dz;
        }
        double lmin, lsum;
        eig3(c00, c11, c22, c01, c02, c12, ngx, ngy, ngz, lmin, lsum);
        svg = lmin / lsum;
    } else if (w <= 2) {
        // Patch kNN half-scan (local indices).
        #pragma unroll
        for (int m = 0; m < KNN; ++m) pl[m] = 0xFFFFFFFFu;
        const int c0r = (w == 1) ? 0 : 128;
        #pragma unroll 1
        for (int j = c0r; j < c0r + 128; ++j) {
            float4 c = pbuf4[j];
            unsigned k = mkkey(dist2(qx, qy, qz, c), (unsigned)j);
            if (k < pl[KNN - 1]) insert16(k, pl);
        }
        if (w == 2) {
            #pragma unroll
            for (int m = 0; m < KNN; ++m) pListBuf[q * KNN + m] = pl[m];
        }
    }
    __syncthreads();   // B2: wave2's half-list ready

    if (w == 1) {
        for (int m = 0; m < KNN; ++m) {
            unsigned key = pListBuf[q * KNN + m];
            if (key >= pl[KNN - 1]) break;
            insert16(key, pl);
        }
        double c00 = 0, c11 = 0, c22 = 0, c01 = 0, c02 = 0, c12 = 0;
        const double qxd = qx, qyd = qy, qzd = qz;
        #pragma unroll
        for (int m = 0; m < KNN; ++m) {
            int idx = (int)(pl[m] & 0x1FFFu);
            float4 cpt = pbuf4[idx];
            double dx = (double)cpt.x - qxd;
            double dy = (double)cpt.y - qyd;
            double dz = (double)cpt.z - qzd;
            c00 += dx * dx; c11 += dy * dy; c22 += dz * dz;
            c01 += dx * dy; c02 += dx * dz; c12 += dy * dz;
        }
        double nx, ny, nz, lmin, lsum;
        eig3(c00, c11, c22, c01, c02, c12, nx, ny, nz, lmin, lsum);
        xbuf[q * 4 + 0] = nx;
        xbuf[q * 4 + 1] = ny;
        xbuf[q * 4 + 2] = nz;
        xbuf[q * 4 + 3] = lmin / lsum;
    }
    __syncthreads();   // B3: patch results ready

    if (w == 0) {
        double npx = xbuf[q * 4 + 0];
        double npy = xbuf[q * 4 + 1];
        double npz = xbuf[q * 4 + 2];
        double svp = xbuf[q * 4 + 3];
        double dx = fabs(npx) - fabs(ngx);
        double dy = fabs(npy) - fabs(ngy);
        double dz = fabs(npz) - fabs(ngz);
        double ln  = sqrt(dx * dx + dy * dy + dz * dz);
        double ds  = svp - svg;
        double lsv = ds * ds;
        #pragma unroll
        for (int o = 32; o > 0; o >>= 1) {
            ln  += __shfl_down(ln, o);
            lsv += __shfl_down(lsv, o);
        }
        if (q == 0) {
            const double inv = 1.0 / (double)(NBATCH * NPTS);
            atomicAdd(&out[0], (float)(ln * inv));
            atomicAdd(&out[1], (float)(lsv * inv));
        }
    }
}

extern "C" void kernel_launch(void* const* d_in, const int* in_sizes, int n_in,
                              void* d_out, int out_size, void* d_ws, size_t ws_size,
                              hipStream_t stream)
{
    const float* pts = (const float*)d_in[0];
    float* out = (float*)d_out;
    hipLaunchKernelGGL(zero2_kernel, dim3(1), dim3(1), 0, stream, out);
    dim3 grid(NPATCH, 4, NBATCH);
    hipLaunchKernelGGL(spl_main, grid, dim3(256), 0, stream, pts, out);
}